// Round 2
// baseline (467.071 us; speedup 1.0000x reference)
//
#include <hip/hip_runtime.h>
#include <stdint.h>

typedef __attribute__((ext_vector_type(8))) __bf16 bf16x8;
typedef __attribute__((ext_vector_type(16))) float f32x16;
typedef __attribute__((ext_vector_type(4))) unsigned int u32x4;
typedef __attribute__((ext_vector_type(4))) float f32x4;
typedef unsigned int u32;
typedef unsigned short u16;

#define THETA 0.7f

__host__ __device__ constexpr float pht_val(int q) {
  return (q == 12) ? (-4.0f + 1e-6f)
       : (q == 7 || q == 11 || q == 13 || q == 17) ? (1.0f + 1e-6f)
       : 1e-6f;
}

__device__ __forceinline__ u16 f2bf(float v) {
  u32 u = __builtin_bit_cast(u32, v);
  return (u16)((u + 0x7fffu + ((u >> 16) & 1u)) >> 16);
}

// ---------------- kernel 1: build K_eff packed as MFMA A-frags + zero pad --
__global__ __launch_bounds__(256) void k_prep(const float* __restrict__ wgt,
                                              const float* __restrict__ alpha,
                                              u16* __restrict__ apack,
                                              u32* __restrict__ zpad) {
  if (blockIdx.x == 0) zpad[threadIdx.x] = 0;   // 1 KB zero source
  int t = blockIdx.x * 256 + threadIdx.x;       // 4096 threads: (o, ci)
  int o = t >> 6, ci = t & 63;
  const float* wp = wgt + ((size_t)(o * 64 + ci)) * 25;
  float wv[25], sumw = 0.f;
#pragma unroll
  for (int p = 0; p < 25; ++p) { wv[p] = wp[p]; sumw += wv[p]; }
  float keff[25];
#pragma unroll
  for (int p = 0; p < 25; ++p) keff[p] = pht_val(p) * wv[p];  // a=0 identity
  constexpr int TP[33] = {0,1,2,3,4,6,7,9,12,13,  0,1,2,3,4,  0, 0, 0,
                          0,5,10,15,20,  0,5,6,10,11,12,15,17,20,21};
  constexpr int TQ[33] = {5,6,12,17,23,10,16,22,20,21,  0,5,10,15,20,  5, 0, 5,
                          0,6,7,8,9,  5,6,2,12,8,4,17,9,23,14};
#pragma unroll
  for (int e = 0; e < 33; ++e) keff[TP[e]] += pht_val(TQ[e]) * wv[TQ[e]];

  float al = alpha[0];
  int kc = ci >> 4, oh = o >> 5;
  int lane = ((ci >> 3) & 1) * 32 + (o & 31);   // A-frag: lane=(k/8)*32+m
#pragma unroll
  for (int p = 0; p < 25; ++p) {
    float v = al * (keff[p] * 0.125f);
    if (p == 12) v -= THETA * sumw;             // fold 1x1 branch into center
    size_t idx = ((((size_t)p * 4 + kc) * 2 + oh) * 64 + lane) * 8 + (ci & 7);
    apack[idx] = f2bf(v);
  }
}

// ---------------- kernel 2: x (NCHW fp32) -> X_t[n][y][px][i] bf16 --------
__global__ __launch_bounds__(256) void k_xcast(const float* __restrict__ x,
                                               u16* __restrict__ xt) {
  __shared__ u16 lt[64][130];
  int bid = blockIdx.x;                       // n*128 + y
  int n = bid >> 7, y = bid & 127;
  const float* xb = x + (size_t)n * 64 * 16384 + (size_t)y * 128;
  int t = threadIdx.x;
#pragma unroll
  for (int it = 0; it < 8; ++it) {            // float4 reads
    int idx = it * 256 + t;
    int i = idx >> 5, p4 = (idx & 31) * 4;
    f32x4 v = *(const f32x4*)(xb + (size_t)i * 16384 + p4);
    lt[i][p4 + 0] = f2bf(v.x); lt[i][p4 + 1] = f2bf(v.y);
    lt[i][p4 + 2] = f2bf(v.z); lt[i][p4 + 3] = f2bf(v.w);
  }
  __syncthreads();
  u32* xtb = (u32*)(xt + (size_t)(n * 128 + y) * 8192);
#pragma unroll
  for (int it = 0; it < 16; ++it) {           // u32 writes (2 i per lane)
    int idx = it * 256 + t;
    int px = idx >> 5, i2 = idx & 31;
    u32 w = (u32)lt[2 * i2][px] | ((u32)lt[2 * i2 + 1][px] << 16);
    xtb[(size_t)px * 32 + i2] = w;
  }
}

// ---------------- kernel 3: conv, 8-row JIT ring + counted vmcnt ----------
// 256 blocks (n x 8 y-chunks of 16 rows), 512 thr = 8 waves = q(4) x ph(2).
// Wave: 64o x 1row x 64px. LDS: 8-row ring (128 cols x 128 B, XOR-swizzled
// granules) + 1 zero-row for halo. Per 4-row iter: 5 dy-phases, phases 1..4
// each stage one row (2 global_load_lds/wave), wait vmcnt(8), raw s_barrier.
#define RROW 16384
#define ZOFF 131072   // 8*RROW

__global__ __launch_bounds__(512, 2) void k_conv(const u16* __restrict__ xt,
                                                 const u32x4* __restrict__ apv,
                                                 const char* __restrict__ zpad,
                                                 float* __restrict__ out) {
  __shared__ char tile[ZOFF + RROW];          // 147456 B
  int bid = blockIdx.x;
  int n = bid >> 3, yc = bid & 7;
  int y0 = yc << 4;
  int tid = threadIdx.x;
  int l = tid & 63, wv = tid >> 6;
  int q = wv >> 1, ph = wv & 1;
  int l31 = l & 31, lhi = l >> 5;

  // zero-row init
  { u32x4 z = {0u, 0u, 0u, 0u};
    *(u32x4*)(tile + ZOFF + tid * 32) = z;
    *(u32x4*)(tile + ZOFF + tid * 32 + 16) = z; }

  // per-lane constant source offset (pre-swizzled: granule g stores src g^ (col&7))
  int soff = ((l >> 3) << 7) + (((l & 7) ^ ((l >> 3) & 7)) << 4);
  const char* xtb = (const char*)xt + (size_t)n * (128u * (size_t)RROW);

  auto STAGE = [&](int r) {                   // stage src row r (2 loads/wave)
    int slot = (r + 16) & 7;
    char* dst = tile + slot * RROW + (wv * 2) * 1024 + l * 16;
    const char* s0, * s1;
    if ((unsigned)r < 128u) {
      const char* rb = xtb + (size_t)r * RROW + soff;
      s0 = rb + (wv * 2) * 1024;  s1 = s0 + 1024;
    } else {
      s0 = zpad + l * 16;  s1 = s0;           // OOB row -> zeros
    }
    __builtin_amdgcn_global_load_lds((const __attribute__((address_space(1))) u32*)s0,
                                     (__attribute__((address_space(3))) u32*)dst, 16, 0, 0);
    __builtin_amdgcn_global_load_lds((const __attribute__((address_space(1))) u32*)s1,
                                     (__attribute__((address_space(3))) u32*)(dst + 1024), 16, 0, 0);
  };

  // precomputed per-(dx,nt) column byte offsets; OOB cols -> LDS zero-row
  int colA[5][2], selA[5][2], c7A[5];
#pragma unroll
  for (int dx = 0; dx < 5; ++dx) {
    c7A[dx] = (ph * 64 + l31 + dx - 2) & 7;   // nt*32 doesn't change &7
#pragma unroll
    for (int nt = 0; nt < 2; ++nt) {
      int col = ph * 64 + nt * 32 + l31 + dx - 2;
      bool v = (unsigned)col < 128u;
      colA[dx][nt] = v ? (col << 7) : (ZOFF + ((col & 127) << 7));
      selA[dx][nt] = v ? ~0 : 0;
    }
  }

  f32x16 a00 = 0, a01 = 0, a10 = 0, a11 = 0;

  // prologue: rows y0-2 .. y0+5, full drain once
#pragma unroll
  for (int r = 0; r < 8; ++r) STAGE(y0 + r - 2);
  asm volatile("s_waitcnt vmcnt(0) lgkmcnt(0)" ::: "memory");
  __builtin_amdgcn_s_barrier();

  for (int t = 0; t < 4; ++t) {
    int y = y0 + t * 4;
#pragma unroll
    for (int j = 0; j < 5; ++j) {             // dy = j
      if (j > 0) {
        STAGE(y + 5 + j);
        asm volatile("s_waitcnt vmcnt(8)" ::: "memory");  // counted, never 0
        __builtin_amdgcn_s_barrier();
      }
      int slotb = ((y + q + j - 2 + 16) & 7) * RROW;      // wave-uniform
#pragma unroll
      for (int dx = 0; dx < 5; ++dx) {
        int p = j * 5 + dx;
        const u32x4* ap = apv + (size_t)p * 512 + l;
#pragma unroll
        for (int kc = 0; kc < 4; ++kc) {
          u32x4 av0 = ap[kc * 128];           // oh=0 (L1-hot, shared by waves)
          u32x4 av1 = ap[kc * 128 + 64];      // oh=1
          int gx = ((kc * 2 + lhi) ^ c7A[dx]) << 4;
          u32x4 b0 = *(const u32x4*)(tile + ((selA[dx][0] & slotb) + colA[dx][0] + gx));
          u32x4 b1 = *(const u32x4*)(tile + ((selA[dx][1] & slotb) + colA[dx][1] + gx));
          a00 = __builtin_amdgcn_mfma_f32_32x32x16_bf16(
              __builtin_bit_cast(bf16x8, av0), __builtin_bit_cast(bf16x8, b0), a00, 0, 0, 0);
          a01 = __builtin_amdgcn_mfma_f32_32x32x16_bf16(
              __builtin_bit_cast(bf16x8, av0), __builtin_bit_cast(bf16x8, b1), a01, 0, 0, 0);
          a10 = __builtin_amdgcn_mfma_f32_32x32x16_bf16(
              __builtin_bit_cast(bf16x8, av1), __builtin_bit_cast(bf16x8, b0), a10, 0, 0, 0);
          a11 = __builtin_amdgcn_mfma_f32_32x32x16_bf16(
              __builtin_bit_cast(bf16x8, av1), __builtin_bit_cast(bf16x8, b1), a11, 0, 0, 0);
        }
      }
      asm volatile("" ::: "memory");
      __builtin_amdgcn_s_barrier();           // readers done before next stage
    }
    // epilogue: wave q stores output row y+q (all 64 o, its 64-px half)
    float* ob = out + (size_t)n * 64 * 16384 + (size_t)(y + q) * 128 + ph * 64 + l31;
#pragma unroll
    for (int rg = 0; rg < 16; ++rg) {
      int orow = (rg & 3) + 8 * (rg >> 2) + 4 * lhi;
      ob[(size_t)orow * 16384]              = a00[rg];
      ob[(size_t)orow * 16384 + 32]         = a01[rg];
      ob[(size_t)(orow + 32) * 16384]       = a10[rg];
      ob[(size_t)(orow + 32) * 16384 + 32]  = a11[rg];
    }
    a00 = 0; a01 = 0; a10 = 0; a11 = 0;
  }
}

extern "C" void kernel_launch(void* const* d_in, const int* in_sizes, int n_in,
                              void* d_out, int out_size, void* d_ws, size_t ws_size,
                              hipStream_t stream) {
  const float* x     = (const float*)d_in[0];   // (32,64,128,128) fp32
  const float* wgt   = (const float*)d_in[1];   // (64,64,5,5) fp32
  const float* alpha = (const float*)d_in[2];   // (1,) fp32
  float* out = (float*)d_out;

  u16* apack = (u16*)d_ws;                                  // 204800 B
  u32* zpad  = (u32*)((char*)d_ws + (256 << 10));           // 1 KB zeros
  u16* xt    = (u16*)((char*)d_ws + (1 << 20));             // 64 MiB

  k_prep <<<16,   256, 0, stream>>>(wgt, alpha, apack, zpad);
  k_xcast<<<4096, 256, 0, stream>>>(x, xt);
  k_conv <<<256,  512, 0, stream>>>(xt, (const u32x4*)apack, (const char*)zpad, out);
}

// Round 3
// 190.476 us; speedup vs baseline: 2.4521x; 2.4521x over previous
//
#include <hip/hip_runtime.h>
#include <stdint.h>

typedef __attribute__((ext_vector_type(8))) __bf16 bf16x8;
typedef __attribute__((ext_vector_type(16))) float f32x16;
typedef __attribute__((ext_vector_type(4))) unsigned int u32x4;
typedef __attribute__((ext_vector_type(4))) float f32x4;
typedef unsigned int u32;
typedef unsigned short u16;

#define THETA 0.7f

__host__ __device__ constexpr float pht_val(int q) {
  return (q == 12) ? (-4.0f + 1e-6f)
       : (q == 7 || q == 11 || q == 13 || q == 17) ? (1.0f + 1e-6f)
       : 1e-6f;
}

__device__ __forceinline__ u16 f2bf(float v) {
  u32 u = __builtin_bit_cast(u32, v);
  return (u16)((u + 0x7fffu + ((u >> 16) & 1u)) >> 16);
}

// ---------------- kernel 1: build K_eff, packed as MFMA A-fragments -------
__global__ __launch_bounds__(256) void k_prep(const float* __restrict__ wgt,
                                              const float* __restrict__ alpha,
                                              u16* __restrict__ apack) {
  int t = blockIdx.x * 256 + threadIdx.x;   // 4096 threads: (o, ci)
  int o = t >> 6, ci = t & 63;
  const float* wp = wgt + ((size_t)(o * 64 + ci)) * 25;
  float wv[25], sumw = 0.f;
#pragma unroll
  for (int p = 0; p < 25; ++p) { wv[p] = wp[p]; sumw += wv[p]; }
  float keff[25];
#pragma unroll
  for (int p = 0; p < 25; ++p) keff[p] = pht_val(p) * wv[p];  // a=0 (identity)
  constexpr int TP[33] = {0,1,2,3,4,6,7,9,12,13,  0,1,2,3,4,  0, 0, 0,
                          0,5,10,15,20,  0,5,6,10,11,12,15,17,20,21};
  constexpr int TQ[33] = {5,6,12,17,23,10,16,22,20,21,  0,5,10,15,20,  5, 0, 5,
                          0,6,7,8,9,  5,6,2,12,8,4,17,9,23,14};
#pragma unroll
  for (int e = 0; e < 33; ++e) keff[TP[e]] += pht_val(TQ[e]) * wv[TQ[e]];

  float al = alpha[0];
  int kc = ci >> 4, oh = o >> 5;
  int lane = ((ci >> 3) & 1) * 32 + (o & 31);   // A-frag: lane=(k/8)*32+m
#pragma unroll
  for (int p = 0; p < 25; ++p) {
    float v = al * (keff[p] * 0.125f);
    if (p == 12) v -= THETA * sumw;             // fold 1x1 branch into center
    size_t idx = ((((size_t)p * 4 + kc) * 2 + oh) * 64 + lane) * 8 + (ci & 7);
    apack[idx] = f2bf(v);
  }
}

// ---------------- kernel 2: x (NCHW fp32) -> X_t[n][y][px][i] bf16 --------
__global__ __launch_bounds__(256) void k_xcast(const float* __restrict__ x,
                                               u16* __restrict__ xt) {
  __shared__ u16 lt[64][130];
  int bid = blockIdx.x;                       // n*128 + y
  int n = bid >> 7, y = bid & 127;
  const float* xb = x + (size_t)n * 64 * 16384 + (size_t)y * 128;
  int t = threadIdx.x;
#pragma unroll
  for (int it = 0; it < 8; ++it) {            // float4 reads
    int idx = it * 256 + t;
    int i = idx >> 5, p4 = (idx & 31) * 4;
    f32x4 v = *(const f32x4*)(xb + (size_t)i * 16384 + p4);
    lt[i][p4 + 0] = f2bf(v.x); lt[i][p4 + 1] = f2bf(v.y);
    lt[i][p4 + 2] = f2bf(v.z); lt[i][p4 + 3] = f2bf(v.w);
  }
  __syncthreads();
  u32* xtb = (u32*)(xt + (size_t)(n * 128 + y) * 8192);
#pragma unroll
  for (int it = 0; it < 16; ++it) {           // u32 writes (2 i per lane)
    int idx = it * 256 + t;
    int px = idx >> 5, i2 = idx & 31;
    u32 w = (u32)lt[2 * i2][px] | ((u32)lt[2 * i2 + 1][px] << 16);
    xtb[(size_t)px * 32 + i2] = w;
  }
}

// ---------------- kernel 3: conv via 32x32x16 bf16 MFMA -------------------
// Round-1 structure (one-shot stage of 8 rows, __syncthreads, compute).
// ONE change: wave = (q = out row, ph = px half) instead of (q, o half);
// each wave computes all 64 o for its 64 px, so every B ds_read feeds
// 2 MFMAs -> ds_read count halves (1600/block vs 3200).
#define ROWB 16896   // 132 cols * 128 B

__global__ __launch_bounds__(512) void k_conv(const u16* __restrict__ xt,
                                              const u32x4* __restrict__ apv,
                                              float* __restrict__ out) {
  __shared__ u32x4 tile4[8 * ROWB / 16];
  char* tile = (char*)tile4;
  int bid = blockIdx.x;
  int lg = (bid & 7) * 128 + (bid >> 3);      // bijective XCD swizzle (1024%8==0)
  int n = lg >> 5, yt = lg & 31;
  int y0 = yt * 4;
  int tid = threadIdx.x;
  int l = tid & 63, wv = tid >> 6;

  // ---- stage: wave wv stages LDS row wv (src row y0+wv-2), swizzled src ----
  {
    int sy = y0 + wv - 2;
    char* rowbase = tile + wv * ROWB;
    if ((unsigned)sy < 128u) {
      const char* src = (const char*)(xt + (size_t)(n * 128 + sy) * 8192);
      int lo3 = l >> 3, l7 = l & 7;
      int glog = l7 ^ ((2 + lo3) & 7);        // inverse swizzle on source
      int soff = lo3 * 128 + glog * 16;
#pragma unroll
      for (int it = 0; it < 16; ++it) {       // 16 x 1KB = full 128-px row
        __builtin_amdgcn_global_load_lds(
            (const __attribute__((address_space(1))) u32*)(src + it * 1024 + soff),
            (__attribute__((address_space(3))) u32*)(rowbase + 256 + it * 1024),
            16, 0, 0);
      }
      if (l < 32) {                           // zero halo cols {0,1,130,131}
        int ii = l >> 3;
        int c = ii + ((ii >> 1) * 128);
        u32x4 z = {0u, 0u, 0u, 0u};
        *(u32x4*)(rowbase + c * 128 + (l & 7) * 16) = z;
      }
    } else {                                  // out-of-image row -> zeros
      u32x4 z = {0u, 0u, 0u, 0u};
#pragma unroll
      for (int it = 0; it < 17; ++it) {
        int off = it * 1024 + l * 16;
        if (off < ROWB) *(u32x4*)(rowbase + off) = z;
      }
    }
  }
  __syncthreads();

  // ---- compute: wave = (q = output row 0..3, ph = px half 0..1) ----
  int q = wv >> 1, ph = wv & 1;
  int l31 = l & 31, lhi = l >> 5;
  f32x16 a00 = 0, a01 = 0, a10 = 0, a11 = 0;
  const u32x4* apb = apv + l;
  for (int p = 0; p < 25; ++p) {
    int dy = p / 5, dx = p % 5;
    const u32x4* ap = apb + (size_t)p * 512;
    const char* pb = tile + (q + dy) * ROWB + (ph * 64 + l31 + dx) * 128;
    int c7 = (l31 + dx) & 7;                  // ph*64, nt*32 don't change &7
#pragma unroll
    for (int kc = 0; kc < 4; ++kc) {
      u32x4 av0 = ap[kc * 128];               // oh=0 A-frag (L1-hot)
      u32x4 av1 = ap[kc * 128 + 64];          // oh=1 A-frag
      int gx = ((kc * 2 + lhi) ^ c7) << 4;    // swizzled granule offset
      u32x4 b0 = *(const u32x4*)(pb + gx);
      u32x4 b1 = *(const u32x4*)(pb + 4096 + gx);
      a00 = __builtin_amdgcn_mfma_f32_32x32x16_bf16(
          __builtin_bit_cast(bf16x8, av0), __builtin_bit_cast(bf16x8, b0), a00, 0, 0, 0);
      a10 = __builtin_amdgcn_mfma_f32_32x32x16_bf16(
          __builtin_bit_cast(bf16x8, av1), __builtin_bit_cast(bf16x8, b0), a10, 0, 0, 0);
      a01 = __builtin_amdgcn_mfma_f32_32x32x16_bf16(
          __builtin_bit_cast(bf16x8, av0), __builtin_bit_cast(bf16x8, b1), a01, 0, 0, 0);
      a11 = __builtin_amdgcn_mfma_f32_32x32x16_bf16(
          __builtin_bit_cast(bf16x8, av1), __builtin_bit_cast(bf16x8, b1), a11, 0, 0, 0);
    }
  }

  // ---- epilogue: C/D layout col=lane&31, row=(rg&3)+8*(rg>>2)+4*(lane>>5)
  float* ob = out + (size_t)n * 64 * 16384 + (size_t)(y0 + q) * 128 + ph * 64 + l31;
#pragma unroll
  for (int rg = 0; rg < 16; ++rg) {
    int orow = (rg & 3) + 8 * (rg >> 2) + 4 * lhi;
    ob[(size_t)orow * 16384]             = a00[rg];
    ob[(size_t)orow * 16384 + 32]        = a01[rg];
    ob[(size_t)(orow + 32) * 16384]      = a10[rg];
    ob[(size_t)(orow + 32) * 16384 + 32] = a11[rg];
  }
}

extern "C" void kernel_launch(void* const* d_in, const int* in_sizes, int n_in,
                              void* d_out, int out_size, void* d_ws, size_t ws_size,
                              hipStream_t stream) {
  const float* x     = (const float*)d_in[0];   // (32,64,128,128) fp32
  const float* wgt   = (const float*)d_in[1];   // (64,64,5,5) fp32
  const float* alpha = (const float*)d_in[2];   // (1,) fp32
  float* out = (float*)d_out;

  u16* apack = (u16*)d_ws;                                  // 204800 B
  u16* xt    = (u16*)((char*)d_ws + (1 << 20));             // 64 MiB

  k_prep <<<16,   256, 0, stream>>>(wgt, alpha, apack);
  k_xcast<<<4096, 256, 0, stream>>>(x, xt);
  k_conv <<<1024, 512, 0, stream>>>(xt, (const u32x4*)apack, out);
}

// Round 4
// 169.837 us; speedup vs baseline: 2.7501x; 1.1215x over previous
//
#include <hip/hip_runtime.h>
#include <stdint.h>

typedef __attribute__((ext_vector_type(8))) __bf16 bf16x8;
typedef __attribute__((ext_vector_type(16))) float f32x16;
typedef __attribute__((ext_vector_type(4))) unsigned int u32x4;
typedef __attribute__((ext_vector_type(4))) float f32x4;
typedef unsigned int u32;
typedef unsigned short u16;

#define THETA 0.7f

__host__ __device__ constexpr float pht_val(int q) {
  return (q == 12) ? (-4.0f + 1e-6f)
       : (q == 7 || q == 11 || q == 13 || q == 17) ? (1.0f + 1e-6f)
       : 1e-6f;
}

__device__ __forceinline__ u16 f2bf(float v) {
  u32 u = __builtin_bit_cast(u32, v);
  return (u16)((u + 0x7fffu + ((u >> 16) & 1u)) >> 16);
}

// ---------------- kernel 1: build K_eff, packed as MFMA A-fragments -------
__global__ __launch_bounds__(256) void k_prep(const float* __restrict__ wgt,
                                              const float* __restrict__ alpha,
                                              u16* __restrict__ apack) {
  int t = blockIdx.x * 256 + threadIdx.x;   // 4096 threads: (o, ci)
  int o = t >> 6, ci = t & 63;
  const float* wp = wgt + ((size_t)(o * 64 + ci)) * 25;
  float wv[25], sumw = 0.f;
#pragma unroll
  for (int p = 0; p < 25; ++p) { wv[p] = wp[p]; sumw += wv[p]; }
  float keff[25];
#pragma unroll
  for (int p = 0; p < 25; ++p) keff[p] = pht_val(p) * wv[p];  // a=0 (identity)
  constexpr int TP[33] = {0,1,2,3,4,6,7,9,12,13,  0,1,2,3,4,  0, 0, 0,
                          0,5,10,15,20,  0,5,6,10,11,12,15,17,20,21};
  constexpr int TQ[33] = {5,6,12,17,23,10,16,22,20,21,  0,5,10,15,20,  5, 0, 5,
                          0,6,7,8,9,  5,6,2,12,8,4,17,9,23,14};
#pragma unroll
  for (int e = 0; e < 33; ++e) keff[TP[e]] += pht_val(TQ[e]) * wv[TQ[e]];

  float al = alpha[0];
  int kc = ci >> 4, oh = o >> 5;
  int lane = ((ci >> 3) & 1) * 32 + (o & 31);   // A-frag: lane=(k/8)*32+m
#pragma unroll
  for (int p = 0; p < 25; ++p) {
    float v = al * (keff[p] * 0.125f);
    if (p == 12) v -= THETA * sumw;             // fold 1x1 branch into center
    size_t idx = ((((size_t)p * 4 + kc) * 2 + oh) * 64 + lane) * 8 + (ci & 7);
    apack[idx] = f2bf(v);
  }
}

// ---------------- kernel 2: x (NCHW fp32) -> X_t[n][y][px][i] bf16 --------
__global__ __launch_bounds__(256) void k_xcast(const float* __restrict__ x,
                                               u16* __restrict__ xt) {
  __shared__ u16 lt[64][130];
  int bid = blockIdx.x;                       // n*128 + y
  int n = bid >> 7, y = bid & 127;
  const float* xb = x + (size_t)n * 64 * 16384 + (size_t)y * 128;
  int t = threadIdx.x;
#pragma unroll
  for (int it = 0; it < 8; ++it) {            // float4 reads
    int idx = it * 256 + t;
    int i = idx >> 5, p4 = (idx & 31) * 4;
    f32x4 v = *(const f32x4*)(xb + (size_t)i * 16384 + p4);
    lt[i][p4 + 0] = f2bf(v.x); lt[i][p4 + 1] = f2bf(v.y);
    lt[i][p4 + 2] = f2bf(v.z); lt[i][p4 + 3] = f2bf(v.w);
  }
  __syncthreads();
  u32* xtb = (u32*)(xt + (size_t)(n * 128 + y) * 8192);
#pragma unroll
  for (int it = 0; it < 16; ++it) {           // u32 writes (2 i per lane)
    int idx = it * 256 + t;
    int px = idx >> 5, i2 = idx & 31;
    u32 w = (u32)lt[2 * i2][px] | ((u32)lt[2 * i2 + 1][px] << 16);
    xtb[(size_t)px * 32 + i2] = w;
  }
}

// ---------------- kernel 3: conv via 32x32x16 bf16 MFMA -------------------
// Row-reuse structure: 256 thr = 4 waves = (oh = o-half, ph = px-half).
// Each wave owns ALL 4 output rows: per (dx,kc) it loads 8 row-frags x 2nt
// from LDS ONCE (16 ds_read_b128) + 5 hoisted A-frags, then issues 40 MFMAs.
// ds:MFMA = 16:40 (vs 16:16 in R1), A-loads hoisted & 1 oh per wave.
#define ROWB 16896   // 132 cols * 128 B

__global__ __launch_bounds__(256, 1) void k_conv(const u16* __restrict__ xt,
                                                 const u32x4* __restrict__ apv,
                                                 float* __restrict__ out) {
  __shared__ u32x4 tile4[8 * ROWB / 16];
  char* tile = (char*)tile4;
  int bid = blockIdx.x;
  int lg = (bid & 7) * 128 + (bid >> 3);      // bijective XCD swizzle (1024%8==0)
  int n = lg >> 5, yt = lg & 31;
  int y0 = yt * 4;
  int tid = threadIdx.x;
  int l = tid & 63, wv = tid >> 6;            // 4 waves

  // ---- stage: wave wv stages tile rows 2wv, 2wv+1 (pre-swizzled source) ----
#pragma unroll
  for (int rr = 0; rr < 2; ++rr) {
    int r = 2 * wv + rr;
    int sy = y0 + r - 2;
    char* rowbase = tile + r * ROWB;
    if ((unsigned)sy < 128u) {
      const char* src = (const char*)(xt + (size_t)(n * 128 + sy) * 8192);
      int lo3 = l >> 3, l7 = l & 7;
      int glog = l7 ^ ((2 + lo3) & 7);        // inverse swizzle on source
      int soff = lo3 * 128 + glog * 16;
#pragma unroll
      for (int it = 0; it < 16; ++it) {       // 16 x 1KB = full 128-px row
        __builtin_amdgcn_global_load_lds(
            (const __attribute__((address_space(1))) u32*)(src + it * 1024 + soff),
            (__attribute__((address_space(3))) u32*)(rowbase + 256 + it * 1024),
            16, 0, 0);
      }
      if (l < 32) {                           // zero halo cols {0,1,130,131}
        int ii = l >> 3;
        int c = ii + ((ii >> 1) * 128);
        u32x4 z = {0u, 0u, 0u, 0u};
        *(u32x4*)(rowbase + c * 128 + (l & 7) * 16) = z;
      }
    } else {                                  // out-of-image row -> zeros
      u32x4 z = {0u, 0u, 0u, 0u};
#pragma unroll
      for (int it = 0; it < 17; ++it) {
        int off = it * 1024 + l * 16;
        if (off < ROWB) *(u32x4*)(rowbase + off) = z;
      }
    }
  }
  __syncthreads();

  // ---- compute: wave = (oh = o-half, ph = px-half), all 4 rows ----
  int oh = wv >> 1, ph = wv & 1;
  int l31 = l & 31, lhi = l >> 5;
  f32x16 a00 = 0, a01 = 0, a10 = 0, a11 = 0;  // acc[q][nt]
  f32x16 a20 = 0, a21 = 0, a30 = 0, a31 = 0;
  const u32x4* apb = apv + (size_t)(oh * 64 + l);
  const char* pcol = tile + (ph * 64 + l31) * 128;

#pragma unroll
  for (int dx = 0; dx < 5; ++dx) {
    int c7 = (l31 + dx) & 7;                  // ph*64, nt*32 don't change &7
    const char* pb = pcol + dx * 128;
#pragma unroll
    for (int kc = 0; kc < 4; ++kc) {
      int gx = ((kc * 2 + lhi) ^ c7) << 4;    // swizzled granule offset
      u32x4 br[8][2];
#pragma unroll
      for (int r = 0; r < 8; ++r) {
        br[r][0] = *(const u32x4*)(pb + r * ROWB + gx);
        br[r][1] = *(const u32x4*)(pb + r * ROWB + 4096 + gx);
      }
      u32x4 af[5];
#pragma unroll
      for (int dy = 0; dy < 5; ++dy)
        af[dy] = apb[(size_t)(dy * 5 + dx) * 512 + kc * 128];
#pragma unroll
      for (int dy = 0; dy < 5; ++dy) {
        bf16x8 A = __builtin_bit_cast(bf16x8, af[dy]);
        a00 = __builtin_amdgcn_mfma_f32_32x32x16_bf16(A, __builtin_bit_cast(bf16x8, br[dy][0]),     a00, 0, 0, 0);
        a01 = __builtin_amdgcn_mfma_f32_32x32x16_bf16(A, __builtin_bit_cast(bf16x8, br[dy][1]),     a01, 0, 0, 0);
        a10 = __builtin_amdgcn_mfma_f32_32x32x16_bf16(A, __builtin_bit_cast(bf16x8, br[dy + 1][0]), a10, 0, 0, 0);
        a11 = __builtin_amdgcn_mfma_f32_32x32x16_bf16(A, __builtin_bit_cast(bf16x8, br[dy + 1][1]), a11, 0, 0, 0);
        a20 = __builtin_amdgcn_mfma_f32_32x32x16_bf16(A, __builtin_bit_cast(bf16x8, br[dy + 2][0]), a20, 0, 0, 0);
        a21 = __builtin_amdgcn_mfma_f32_32x32x16_bf16(A, __builtin_bit_cast(bf16x8, br[dy + 2][1]), a21, 0, 0, 0);
        a30 = __builtin_amdgcn_mfma_f32_32x32x16_bf16(A, __builtin_bit_cast(bf16x8, br[dy + 3][0]), a30, 0, 0, 0);
        a31 = __builtin_amdgcn_mfma_f32_32x32x16_bf16(A, __builtin_bit_cast(bf16x8, br[dy + 3][1]), a31, 0, 0, 0);
      }
    }
  }

  // ---- epilogue: C/D layout col=lane&31, row=(rg&3)+8*(rg>>2)+4*(lane>>5)
  // out[n][oh*32+orow][y0+q][ph*64+nt*32+l31]
  float* ob = out + ((size_t)(n * 64 + oh * 32) * 128 + y0) * 128 + ph * 64 + l31;
#pragma unroll
  for (int rg = 0; rg < 16; ++rg) {
    int orow = (rg & 3) + 8 * (rg >> 2) + 4 * lhi;
    float* obr = ob + (size_t)orow * 16384;
    obr[0]        = a00[rg];  obr[32]       = a01[rg];
    obr[128]      = a10[rg];  obr[128 + 32] = a11[rg];
    obr[256]      = a20[rg];  obr[256 + 32] = a21[rg];
    obr[384]      = a30[rg];  obr[384 + 32] = a31[rg];
  }
}

extern "C" void kernel_launch(void* const* d_in, const int* in_sizes, int n_in,
                              void* d_out, int out_size, void* d_ws, size_t ws_size,
                              hipStream_t stream) {
  const float* x     = (const float*)d_in[0];   // (32,64,128,128) fp32
  const float* wgt   = (const float*)d_in[1];   // (64,64,5,5) fp32
  const float* alpha = (const float*)d_in[2];   // (1,) fp32
  float* out = (float*)d_out;

  u16* apack = (u16*)d_ws;                                  // 204800 B
  u16* xt    = (u16*)((char*)d_ws + (1 << 20));             // 64 MiB

  k_prep <<<16,   256, 0, stream>>>(wgt, alpha, apack);
  k_xcast<<<4096, 256, 0, stream>>>(x, xt);
  k_conv <<<1024, 256, 0, stream>>>(xt, (const u32x4*)apack, out);
}

// Round 6
// 146.671 us; speedup vs baseline: 3.1845x; 1.1579x over previous
//
#include <hip/hip_runtime.h>
#include <stdint.h>

typedef __attribute__((ext_vector_type(8))) __bf16 bf16x8;
typedef __attribute__((ext_vector_type(16))) float f32x16;
typedef __attribute__((ext_vector_type(4))) unsigned int u32x4;
typedef __attribute__((ext_vector_type(4))) float f32x4;
typedef unsigned int u32;
typedef unsigned short u16;

#define THETA 0.7f

__host__ __device__ constexpr float pht_val(int q) {
  return (q == 12) ? (-4.0f + 1e-6f)
       : (q == 7 || q == 11 || q == 13 || q == 17) ? (1.0f + 1e-6f)
       : 1e-6f;
}

__device__ __forceinline__ u16 f2bf(float v) {
  u32 u = __builtin_bit_cast(u32, v);
  return (u16)((u + 0x7fffu + ((u >> 16) & 1u)) >> 16);
}

// ---------------- kernel 1: build K_eff, packed as MFMA A-fragments -------
__global__ __launch_bounds__(256) void k_prep(const float* __restrict__ wgt,
                                              const float* __restrict__ alpha,
                                              u16* __restrict__ apack) {
  int t = blockIdx.x * 256 + threadIdx.x;   // 4096 threads: (o, ci)
  int o = t >> 6, ci = t & 63;
  const float* wp = wgt + ((size_t)(o * 64 + ci)) * 25;
  float wv[25], sumw = 0.f;
#pragma unroll
  for (int p = 0; p < 25; ++p) { wv[p] = wp[p]; sumw += wv[p]; }
  float keff[25];
#pragma unroll
  for (int p = 0; p < 25; ++p) keff[p] = pht_val(p) * wv[p];  // a=0 (identity)
  constexpr int TP[33] = {0,1,2,3,4,6,7,9,12,13,  0,1,2,3,4,  0, 0, 0,
                          0,5,10,15,20,  0,5,6,10,11,12,15,17,20,21};
  constexpr int TQ[33] = {5,6,12,17,23,10,16,22,20,21,  0,5,10,15,20,  5, 0, 5,
                          0,6,7,8,9,  5,6,2,12,8,4,17,9,23,14};
#pragma unroll
  for (int e = 0; e < 33; ++e) keff[TP[e]] += pht_val(TQ[e]) * wv[TQ[e]];

  float al = alpha[0];
  int kc = ci >> 4, oh = o >> 5;
  int lane = ((ci >> 3) & 1) * 32 + (o & 31);   // A-frag: lane=(k/8)*32+m
#pragma unroll
  for (int p = 0; p < 25; ++p) {
    float v = al * (keff[p] * 0.125f);
    if (p == 12) v -= THETA * sumw;             // fold 1x1 branch into center
    size_t idx = ((((size_t)p * 4 + kc) * 2 + oh) * 64 + lane) * 8 + (ci & 7);
    apack[idx] = f2bf(v);
  }
}

// ---------------- kernel 2: x (NCHW fp32) -> X_t[n][y][px][i] bf16 --------
__global__ __launch_bounds__(256) void k_xcast(const float* __restrict__ x,
                                               u16* __restrict__ xt) {
  __shared__ u16 lt[64][130];
  int bid = blockIdx.x;                       // n*128 + y
  int n = bid >> 7, y = bid & 127;
  const float* xb = x + (size_t)n * 64 * 16384 + (size_t)y * 128;
  int t = threadIdx.x;
#pragma unroll
  for (int it = 0; it < 8; ++it) {            // float4 reads
    int idx = it * 256 + t;
    int i = idx >> 5, p4 = (idx & 31) * 4;
    f32x4 v = *(const f32x4*)(xb + (size_t)i * 16384 + p4);
    lt[i][p4 + 0] = f2bf(v.x); lt[i][p4 + 1] = f2bf(v.y);
    lt[i][p4 + 2] = f2bf(v.z); lt[i][p4 + 3] = f2bf(v.w);
  }
  __syncthreads();
  u32* xtb = (u32*)(xt + (size_t)(n * 128 + y) * 8192);
#pragma unroll
  for (int it = 0; it < 16; ++it) {           // u32 writes (2 i per lane)
    int idx = it * 256 + t;
    int px = idx >> 5, i2 = idx & 31;
    u32 w = (u32)lt[2 * i2][px] | ((u32)lt[2 * i2 + 1][px] << 16);
    xtb[(size_t)px * 32 + i2] = w;
  }
}

// ---------------- kernel 3: conv via 32x32x16 bf16 MFMA -------------------
// R4 dataflow, half-width tile for 2 blocks/CU (occupancy fix).
// Block = 4 rows x 64 px x 64 o; tile = 8 rows x 68 cols x 128 B (ROWB=9216
// padded) = 72 KB. 4 waves = (oh, q32 px-quarter); per (dx,kc): 8 ds_read +
// 5 A-loads -> 20 MFMAs. Halo cols hold real neighbor data (predicated
// global_load_lds; ds_write zeros at image edges / pad).
// BUGFIX vs R5: xt row stride is 16384 BYTES (128 px * 64 ch * 2 B), the
// R5 code used 8192 bytes (u16-element count) -> staged wrong rows.
#define ROWB 9216

__global__ __launch_bounds__(256, 2) void k_conv(const u16* __restrict__ xt,
                                                 const u32x4* __restrict__ apv,
                                                 float* __restrict__ out) {
  __shared__ char tile[8 * ROWB];             // 73728 B
  int bid = blockIdx.x;
  int lg = (bid & 7) * 256 + (bid >> 3);      // XCD swizzle (2048%8==0)
  int ph = lg & 1, yt = (lg >> 1) & 31, n = lg >> 6;
  int y0 = yt * 4, px0 = ph * 64;
  int tid = threadIdx.x;
  int l = tid & 63, wv = tid >> 6;            // 4 waves

  // ---- stage: wave wv stages tile rows 2wv, 2wv+1 (pre-swizzled source) ----
#pragma unroll
  for (int rr = 0; rr < 2; ++rr) {
    int r = 2 * wv + rr;
    int sy = y0 + r - 2;
    char* rowbase = tile + r * ROWB;
    if ((unsigned)sy < 128u) {
      // row byte base shifted so tile col c holds src px = px0 + c - 2
      const char* xrow = (const char*)xt + ((size_t)(n * 128 + sy) * 16384)
                         + (ptrdiff_t)(px0 - 2) * 128;
      int g = l & 7;
#pragma unroll
      for (int it = 0; it < 9; ++it) {        // 576 granule slots >= 544+pad
        int gi = it * 64 + l;
        int c = gi >> 3;
        bool valid = ((unsigned)(px0 + c - 2) < 128u) && (c < 68);
        if (valid) {
          const char* src = xrow + c * 128 + ((g ^ (c & 7)) << 4);
          __builtin_amdgcn_global_load_lds(
              (const __attribute__((address_space(1))) u32*)src,
              (__attribute__((address_space(3))) u32*)(rowbase + it * 1024),
              16, 0, 0);                      // HW adds lane*16
        } else {
          u32x4 z = {0u, 0u, 0u, 0u};
          *(u32x4*)(rowbase + it * 1024 + l * 16) = z;
        }
      }
    } else {                                  // out-of-image row -> zeros
      u32x4 z = {0u, 0u, 0u, 0u};
#pragma unroll
      for (int it = 0; it < 9; ++it)
        *(u32x4*)(rowbase + it * 1024 + l * 16) = z;
    }
  }
  __syncthreads();

  // ---- compute: wave = (oh = o-half, q32 = px quarter), all 4 rows ----
  int oh = wv >> 1, q32 = wv & 1;
  int l31 = l & 31, lhi = l >> 5;
  f32x16 a0 = 0, a1 = 0, a2 = 0, a3 = 0;      // acc[row]
  const u32x4* apb = apv + (size_t)(oh * 64 + l);
  const char* pcol = tile + (q32 * 32 + l31) * 128;

#pragma unroll
  for (int dx = 0; dx < 5; ++dx) {
    int c7 = (l31 + dx) & 7;                  // q32*32 doesn't change &7
    const char* pb = pcol + dx * 128;
#pragma unroll
    for (int kc = 0; kc < 4; ++kc) {
      int gx = ((kc * 2 + lhi) ^ c7) << 4;    // swizzled granule offset
      u32x4 br[8];
#pragma unroll
      for (int j = 0; j < 8; ++j) br[j] = *(const u32x4*)(pb + j * ROWB + gx);
      u32x4 af[5];
#pragma unroll
      for (int dy = 0; dy < 5; ++dy)
        af[dy] = apb[(size_t)(dy * 5 + dx) * 512 + kc * 128];
#pragma unroll
      for (int dy = 0; dy < 5; ++dy) {
        bf16x8 A = __builtin_bit_cast(bf16x8, af[dy]);
        a0 = __builtin_amdgcn_mfma_f32_32x32x16_bf16(A, __builtin_bit_cast(bf16x8, br[dy]),     a0, 0, 0, 0);
        a1 = __builtin_amdgcn_mfma_f32_32x32x16_bf16(A, __builtin_bit_cast(bf16x8, br[dy + 1]), a1, 0, 0, 0);
        a2 = __builtin_amdgcn_mfma_f32_32x32x16_bf16(A, __builtin_bit_cast(bf16x8, br[dy + 2]), a2, 0, 0, 0);
        a3 = __builtin_amdgcn_mfma_f32_32x32x16_bf16(A, __builtin_bit_cast(bf16x8, br[dy + 3]), a3, 0, 0, 0);
      }
    }
  }

  // ---- epilogue: C/D layout col=lane&31, row=(rg&3)+8*(rg>>2)+4*(lane>>5)
  float* ob = out + ((size_t)(n * 64 + oh * 32) * 128 + y0) * 128
              + px0 + q32 * 32 + l31;
#pragma unroll
  for (int rg = 0; rg < 16; ++rg) {
    int orow = (rg & 3) + 8 * (rg >> 2) + 4 * lhi;
    float* obr = ob + (size_t)orow * 16384;
    obr[0]   = a0[rg];
    obr[128] = a1[rg];
    obr[256] = a2[rg];
    obr[384] = a3[rg];
  }
}

extern "C" void kernel_launch(void* const* d_in, const int* in_sizes, int n_in,
                              void* d_out, int out_size, void* d_ws, size_t ws_size,
                              hipStream_t stream) {
  const float* x     = (const float*)d_in[0];   // (32,64,128,128) fp32
  const float* wgt   = (const float*)d_in[1];   // (64,64,5,5) fp32
  const float* alpha = (const float*)d_in[2];   // (1,) fp32
  float* out = (float*)d_out;

  u16* apack = (u16*)d_ws;                                  // 204800 B
  u16* xt    = (u16*)((char*)d_ws + (1 << 20));             // 64 MiB

  k_prep <<<16,   256, 0, stream>>>(wgt, alpha, apack);
  k_xcast<<<4096, 256, 0, stream>>>(x, xt);
  k_conv <<<2048, 256, 0, stream>>>(xt, (const u32x4*)apack, out);
}